// Round 15
// baseline (234.980 us; speedup 1.0000x reference)
//
#include <hip/hip_runtime.h>
#include <math.h>

#define NB 16
#define NH 256
#define NW 256
#define TWO_PI 6.28318530717958647692f
#define FSCALE (1.0f/65536.0f)       // norm='forward' 1/(H*W)

// Workspace layout (float-sized slots). ws_size = 1 GiB; we use 48 MB.
// All intermediates are bf16 packed as u32 (re | im<<16) — cross-dispatch
// stores are >=4B (r10 lesson: 2-byte WS stores diverge under graph replay).
//   [0, 2^23)        G1u[bh][ky][i] u32 cplx (K1->K2); reused as
//                    tmpu[bh][ky][o] u32 cplx (K4->K5).   stride 2048 u32/bh
//   [2^23, +2^21)    Xu[b][kx][ky][i]  u32 cplx (K2->K3)
//   [2^23+2^21,+2^21) ofu[b][kx][ky][o] u32 cplx (K3->K4)
// r14 lesson: v_cvt_pk_bf16_f32 inline asm produced NaN — software f2bf/pk2
// (r12/r13-proven) retained; structure changes kept.
#define OFF_X  ((size_t)1 << 23)
#define OFF_OF (((size_t)1 << 23) + ((size_t)1 << 21))
#define WS_FLOATS_NEEDED (((size_t)1 << 23) + ((size_t)2 << 21))

typedef __attribute__((ext_vector_type(8))) short short8;
typedef __attribute__((ext_vector_type(4))) float f32x4;

__device__ __forceinline__ unsigned short f2bf(float f) {
    unsigned int u = __float_as_uint(f);
    unsigned int r = (u + 0x7FFFu + ((u >> 16) & 1u)) >> 16;
    return (unsigned short)r;
}
__device__ __forceinline__ float bf2f(unsigned int u16) {   // u16: low 16 bits
    return __uint_as_float(u16 << 16);
}
__device__ __forceinline__ unsigned int pk2(float a, float b) {
    return (unsigned int)f2bf(a) | ((unsigned int)f2bf(b) << 16);
}

// ---------------- K1: forward DFT over w via bf16 MFMA ----------------------
// A = x^T (M = i), B = T (N = modes: 0-31 cos->re, 32-63 -sin->im).
// 512 thr / 8 waves: wave = (mtile = wave&3, g = wave>>2) computes n-tiles
// {g, g+2} -> lane holds (re,im) of ky = g*16+col for i = mtile*16+kq*4+q.
// Staging: 4x4-block transpose, pk2 pairs, conflict-free ds_write_b64.
#define XPITCH 264   // ushorts per LDS row (256 + 8 pad)
__global__ __launch_bounds__(512) void k1_dft_w(const float* __restrict__ x,
                                                float* __restrict__ WS) {
    __shared__ float2 tw[256];
    __shared__ unsigned short Al[64 * XPITCH];   // T[mode][w] bf16, 33 KB
    __shared__ unsigned short Xl[64 * XPITCH];   // x^T[i][w] bf16, 33 KB
    int t = threadIdx.x;
    if (t < 256) { float s, c; sincosf(TWO_PI * (float)t * (1.0f/256.0f), &s, &c);
                   tw[t] = make_float2(c, s); }
    __syncthreads();
    {   // build T from tw: thread t covers m = t>>3, w = (t&7)*32 .. +31
        int m = t >> 3, w0T = (t & 7) * 32;
        int ky = m & 31;
#pragma unroll
        for (int d8 = 0; d8 < 4; ++d8) {
            short8 v8;
#pragma unroll
            for (int j = 0; j < 8; ++j) {
                int w = w0T + d8*8 + j;
                float2 cs = tw[(ky * w) & 255];
                float v = (m < 32) ? cs.x : -cs.y;
                v8[j] = (short)f2bf(v * FSCALE);
            }
            *(short8*)&Al[m * XPITCH + w0T + d8*8] = v8;
        }
    }
    int wave = t >> 6, lane = t & 63;
    int col = lane & 15, kq = lane >> 4;         // kq 0..3
    int mtile = wave & 3, g = wave >> 2;
    int wq = t & 15, sub = (t >> 4) & 3;
    unsigned int* Gu = (unsigned int*)WS;
    for (int u = 0; u < 4; ++u) {
        int bh = blockIdx.x * 4 + u;
        __syncthreads();             // T ready / previous MFMA reads done
        const float* xb = x + (size_t)bh * 16384;
#pragma unroll
        for (int p = 0; p < 2; ++p) {
            int i0 = (wave + 8*p) * 4;
            int w0 = sub*64 + wq*4;
            float4 r0 = *(const float4*)(xb + (w0+0)*64 + i0);
            float4 r1 = *(const float4*)(xb + (w0+1)*64 + i0);
            float4 r2 = *(const float4*)(xb + (w0+2)*64 + i0);
            float4 r3 = *(const float4*)(xb + (w0+3)*64 + i0);
            uint2 s0; s0.x = pk2(r0.x, r1.x); s0.y = pk2(r2.x, r3.x);
            *(uint2*)&Xl[(i0+0)*XPITCH + w0] = s0;
            uint2 s1; s1.x = pk2(r0.y, r1.y); s1.y = pk2(r2.y, r3.y);
            *(uint2*)&Xl[(i0+1)*XPITCH + w0] = s1;
            uint2 s2; s2.x = pk2(r0.z, r1.z); s2.y = pk2(r2.z, r3.z);
            *(uint2*)&Xl[(i0+2)*XPITCH + w0] = s2;
            uint2 s3; s3.x = pk2(r0.w, r1.w); s3.y = pk2(r2.w, r3.w);
            *(uint2*)&Xl[(i0+3)*XPITCH + w0] = s3;
        }
        __syncthreads();
        f32x4 a0 = (f32x4){0.f,0.f,0.f,0.f};
        f32x4 a1 = (f32x4){0.f,0.f,0.f,0.f};
#pragma unroll
        for (int kk = 0; kk < 8; ++kk) {
            int k = kk*32 + kq*8;
            short8 af = *(const short8*)&Xl[(mtile*16 + col) * XPITCH + k];
            short8 b0 = *(const short8*)&Al[(g*16 + col) * XPITCH + k];
            short8 b1 = *(const short8*)&Al[((g+2)*16 + col) * XPITCH + k];
            a0 = __builtin_amdgcn_mfma_f32_16x16x32_bf16(af, b0, a0, 0, 0, 0);
            a1 = __builtin_amdgcn_mfma_f32_16x16x32_bf16(af, b1, a1, 0, 0, 0);
        }
        int i0s = mtile*16 + kq*4;
        int ky = g*16 + col;
        uint4 pk;
        pk.x = pk2(a0[0], a1[0]);
        pk.y = pk2(a0[1], a1[1]);
        pk.z = pk2(a0[2], a1[2]);
        pk.w = pk2(a0[3], a1[3]);
        *(uint4*)(Gu + (size_t)bh * 2048 + ky*64 + i0s) = pk;
    }
}

// ---------------- K2: forward DFT over h via bf16 MFMA (h-folded, K=256) -----
// Per (b,ky): X_re[64 kx, 64 i] = A2 · [P_re | M_im], X_im = A2 · [P_im | -M_re]
// A2[kx][s]: s<=128: cos(kx*s); s>128: sin(kx*(s-128)).  1024 thr, 16 waves.
#define K2P 264
__global__ __launch_bounds__(1024) void k2_dft_h(float* __restrict__ WS) {
    int b  = blockIdx.x >> 5;
    int ky = blockIdx.x & 31;
    int t  = threadIdx.x;
    __shared__ float2 tw[256];
    __shared__ unsigned short A2l[64 * K2P];     // 33 KB
    __shared__ unsigned short B1l[64 * K2P];
    __shared__ unsigned short B2l[64 * K2P];
    if (t < 256) { float s, c; sincosf(TWO_PI * (float)t * (1.0f/256.0f), &s, &c);
                   tw[t] = make_float2(c, s); }
    __syncthreads();
    {   // build A2 from tw: thread t covers row r = t>>4, s = (t&15)*16 .. +15
        int r = t >> 4, s0 = (t & 15) * 16;
        int kxe = (r < 32) ? r : r + 192;
#pragma unroll
        for (int c8 = 0; c8 < 2; ++c8) {
            short8 v8;
#pragma unroll
            for (int j = 0; j < 8; ++j) {
                int s = s0 + c8*8 + j;
                float v = (s <= 128) ? tw[(kxe * s) & 255].x
                                     : tw[(kxe * (s - 128)) & 255].y;
                v8[j] = (short)f2bf(v);
            }
            *(short8*)&A2l[r*K2P + s0 + c8*8] = v8;
        }
    }
    // stage + fold G (bf16 in, fp32 fold, bf16 store)
    int i = t & 63, hg = t >> 6;     // hg 0..15
    const unsigned int* gu = (const unsigned int*)WS
                             + (size_t)(b*256)*2048 + ky*64 + i;
    for (int s2 = 0; hg + 16*s2 <= 128; ++s2) {
        int hp = hg + 16*s2;
        unsigned int ga = gu[(size_t)hp*2048];
        float are = bf2f(ga & 0xffffu), aim = bf2f(ga >> 16);
        if (hp == 0 || hp == 128) {
            B1l[i*K2P + hp] = f2bf(are);         // P_re = G
            B2l[i*K2P + hp] = f2bf(aim);         // P_im
        } else {
            unsigned int gb = gu[(size_t)(256-hp)*2048];
            float bre = bf2f(gb & 0xffffu), bim = bf2f(gb >> 16);
            B1l[i*K2P + hp]       = f2bf(are + bre);    // P_re
            B1l[i*K2P + 128 + hp] = f2bf(aim - bim);    // M_im
            B2l[i*K2P + hp]       = f2bf(aim + bim);    // P_im
            B2l[i*K2P + 128 + hp] = f2bf(bre - are);    // -M_re
        }
    }
    __syncthreads();
    int wave = t >> 6, col = t & 15, kq = (t >> 4) & 3;
    int mt = wave >> 2, n = wave & 3;    // one (mt,n) pair per wave
    f32x4 ar = (f32x4){0.f,0.f,0.f,0.f}, ai = (f32x4){0.f,0.f,0.f,0.f};
#pragma unroll
    for (int kk = 0; kk < 8; ++kk) {
        int k = kk*32 + kq*8;
        short8 af = *(const short8*)&A2l[(mt*16 + col)*K2P + k];
        short8 b1 = *(const short8*)&B1l[(n*16 + col)*K2P + k];
        short8 b2 = *(const short8*)&B2l[(n*16 + col)*K2P + k];
        ar = __builtin_amdgcn_mfma_f32_16x16x32_bf16(af, b1, ar, 0, 0, 0);
        ai = __builtin_amdgcn_mfma_f32_16x16x32_bf16(af, b2, ai, 0, 0, 0);
    }
    unsigned int* Xu = (unsigned int*)(WS + OFF_X);
#pragma unroll
    for (int q = 0; q < 4; ++q) {
        int kxrow = mt*16 + kq*4 + q;
        Xu[(((size_t)b*64 + kxrow)*32 + ky)*64 + n*16 + col] = pk2(ar[q], ai[q]);
    }
}

// ---------------- K3: channel mixing (complex 64x64 per (kx,ky)) -------------
__global__ __launch_bounds__(512) void k3_mix(const float* __restrict__ w1re,
                                              const float* __restrict__ w1im,
                                              const float* __restrict__ w2re,
                                              const float* __restrict__ w2im,
                                              float* __restrict__ WS) {
    int kx  = blockIdx.x & 63;       // 0..63
    int kyq = blockIdx.x >> 6;       // 0..3; ky = kyq*8 + kyl
    int t   = threadIdx.x;
    __shared__ float2 lx[8192];      // [b][ky8][i] = 64 KB
    __shared__ float  lw[2][2][4][576];  // [buf][re/im][i4][o*9+ky8] = 36 KB
    const float* wre = (kx < 32) ? w1re : w2re;
    const float* wim = (kx < 32) ? w1im : w2im;
    int m = kx & 31;
    const unsigned int* Xu = (const unsigned int*)(WS + OFF_X);
    for (int n = t; n < 8192; n += 512) {
        int bb = n >> 9, ky8 = (n >> 6) & 7, ii = n & 63;
        unsigned int g = Xu[(((size_t)bb*64 + kx)*32 + kyq*8 + ky8)*64 + ii];
        lx[n] = make_float2(bf2f(g & 0xffffu), bf2f(g >> 16));
    }
    int sarr = t & 1, so = (t >> 1) & 63, si4 = t >> 7;
    const float* wsrc = sarr ? wim : wre;
    size_t sbase = (size_t)m*32 + kyq*8;
    int kyl = t >> 6;                // 0..7
    int o   = t & 63;
    int kyg = kyq*8 + kyl;
    float ar[16], ai[16];
#pragma unroll
    for (int bb = 0; bb < 16; ++bb) { ar[bb] = 0.f; ai[bb] = 0.f; }

    float4 wa, wb;
    {
        const float* src = wsrc + ((size_t)(si4*64 + so)*1024 + sbase);
        wa = *(const float4*)src; wb = *(const float4*)(src + 4);
        float* dst = &lw[0][sarr][si4][so*9];
        dst[0]=wa.x; dst[1]=wa.y; dst[2]=wa.z; dst[3]=wa.w;
        dst[4]=wb.x; dst[5]=wb.y; dst[6]=wb.z; dst[7]=wb.w;
    }
    __syncthreads();

    for (int k = 0; k < 16; ++k) {
        int i0 = k*4;
        float4 na, nb;
        if (k < 15) {
            const float* src = wsrc + ((size_t)((i0+4+si4)*64 + so)*1024 + sbase);
            na = *(const float4*)src; nb = *(const float4*)(src + 4);
        }
#pragma unroll
        for (int di = 0; di < 4; ++di) {
            float wr = lw[k & 1][0][di][o*9 + kyl];
            float wi = lw[k & 1][1][di][o*9 + kyl];
            int ii = i0 + di;
#pragma unroll
            for (int bb = 0; bb < 16; ++bb) {
                float2 xv = lx[(bb*8 + kyl)*64 + ii];
                ar[bb] = fmaf(xv.x, wr, fmaf(-xv.y, wi, ar[bb]));
                ai[bb] = fmaf(xv.x, wi, fmaf( xv.y, wr, ai[bb]));
            }
        }
        if (k < 15) {
            float* dst = &lw[(k+1) & 1][sarr][si4][so*9];
            dst[0]=na.x; dst[1]=na.y; dst[2]=na.z; dst[3]=na.w;
            dst[4]=nb.x; dst[5]=nb.y; dst[6]=nb.z; dst[7]=nb.w;
        }
        __syncthreads();
    }
    unsigned int* ofu = (unsigned int*)(WS + OFF_OF);
#pragma unroll
    for (int bb = 0; bb < 16; ++bb) {
        ofu[(((size_t)bb*64 + kx)*32 + kyg)*64 + o] = pk2(ar[bb], ai[bb]);
    }
}

// ---------------- K4: inverse DFT over h via bf16 MFMA (K=128) ---------------
// Per (b,ky): tmp_re[256 h, 64 o] = A4 · [of_re | -of_im],
//             tmp_im = A4 · [of_im | of_re].  A4[h][s]: s<64 cos, s>=64 sin.
// Staging is pure bit-copy (of already bf16; -im = sign-bit XOR).
#define K4P 136
__global__ __launch_bounds__(1024) void k4_idft_h(float* __restrict__ WS) {
    int b  = blockIdx.x >> 5;
    int ky = blockIdx.x & 31;
    int t  = threadIdx.x;
    __shared__ float2 tw[256];
    __shared__ unsigned short A4l[256 * K4P];    // 68 KB
    __shared__ unsigned short B1l[64 * K4P];     // 17 KB
    __shared__ unsigned short B2l[64 * K4P];
    if (t < 256) { float s, c; sincosf(TWO_PI * (float)t * (1.0f/256.0f), &s, &c);
                   tw[t] = make_float2(c, s); }
    __syncthreads();
    {   // build A4 from tw: thread t covers row h = t>>2, s = (t&3)*32 .. +31
        int h = t >> 2, s0 = (t & 3) * 32;
#pragma unroll
        for (int c8 = 0; c8 < 4; ++c8) {
            short8 v8;
#pragma unroll
            for (int j = 0; j < 8; ++j) {
                int s = s0 + c8*8 + j;
                int ds = s & 63;
                int kxe = (ds < 32) ? ds : ds + 192;
                float2 cs = tw[(kxe * h) & 255];
                v8[j] = (short)f2bf((s < 64) ? cs.x : cs.y);
            }
            *(short8*)&A4l[h*K4P + s0 + c8*8] = v8;
        }
    }
    // stage of-slice (u32 bf16 pairs -> bit-copied B tiles)
    int o = t & 63, kg = t >> 6;     // kg 0..15
    const unsigned int* ofu = (const unsigned int*)(WS + OFF_OF);
#pragma unroll
    for (int s = 0; s < 4; ++s) {
        int kx = kg*4 + s;
        unsigned int g = ofu[(((size_t)b*64 + kx)*32 + ky)*64 + o];
        unsigned short lo = (unsigned short)(g & 0xffffu);
        unsigned short hi = (unsigned short)(g >> 16);
        B1l[o*K4P + kx]      = lo;
        B1l[o*K4P + 64 + kx] = hi ^ 0x8000u;     // -im
        B2l[o*K4P + kx]      = hi;
        B2l[o*K4P + 64 + kx] = lo;
    }
    __syncthreads();
    int wave = t >> 6, col = t & 15, kq = (t >> 4) & 3;
    unsigned int* tmpu = (unsigned int*)WS;
#pragma unroll
    for (int e = 0; e < 4; ++e) {
        int p = wave*4 + e, mt = p >> 2, n = p & 3;
        f32x4 ar = (f32x4){0.f,0.f,0.f,0.f}, ai = (f32x4){0.f,0.f,0.f,0.f};
#pragma unroll
        for (int kk = 0; kk < 4; ++kk) {
            int k = kk*32 + kq*8;
            short8 af = *(const short8*)&A4l[(mt*16 + col)*K4P + k];
            short8 b1 = *(const short8*)&B1l[(n*16 + col)*K4P + k];
            short8 b2 = *(const short8*)&B2l[(n*16 + col)*K4P + k];
            ar = __builtin_amdgcn_mfma_f32_16x16x32_bf16(af, b1, ar, 0, 0, 0);
            ai = __builtin_amdgcn_mfma_f32_16x16x32_bf16(af, b2, ai, 0, 0, 0);
        }
#pragma unroll
        for (int q = 0; q < 4; ++q) {
            int h  = mt*16 + kq*4 + q;
            int o2 = n*16 + col;
            tmpu[(size_t)(b*256 + h)*2048 + ky*64 + o2] = pk2(ar[q], ai[q]);
        }
    }
}

// ---------------- K5: inverse rfft over w via bf16 MFMA + bias ---------------
// 512 thr / 8 waves: wave owns w-slice wave*32..+31 (2 m-tiles x 4 n x 2 kk
// = 16 MFMA per bh).
#define APITCH 72
__global__ __launch_bounds__(512) void k5_idft_w(const float* __restrict__ bias,
                                                 const float* __restrict__ WS,
                                                 float* __restrict__ out) {
    int t = threadIdx.x;
    __shared__ float2 tw[256];
    __shared__ unsigned short T5[256 * APITCH];  // [w][k] bf16, 36 KB
    __shared__ unsigned short Bl[64 * APITCH];   // [o][k] bf16, 9 KB
    if (t < 256) { float s, c; sincosf(TWO_PI * (float)t * (1.0f/256.0f), &s, &c);
                   tw[t] = make_float2(c, s); }
    __syncthreads();
    {   // build T5: thread t covers row w = t>>1, ky-half (t&1)*16
        int w = t >> 1, hf = (t & 1) * 16;
#pragma unroll
        for (int j = 0; j < 16; ++j) {
            int ky = hf + j;
            float2 cs = tw[(ky * w) & 255];
            float sc = ky ? 2.f : 1.f;
            T5[w*APITCH + ky]      = f2bf(sc * cs.x);
            T5[w*APITCH + 32 + ky] = f2bf(-sc * cs.y);
        }
    }
    int o = t & 63, kg = t >> 6;     // staging roles, kg 0..7
    int wave = t >> 6, col = t & 15, kq = (t >> 4) & 3;
    float bv[4];
#pragma unroll
    for (int n = 0; n < 4; ++n) bv[n] = bias[n*16 + col];

    for (int u = 0; u < 4; ++u) {
        int bh = blockIdx.x * 4 + u;
        __syncthreads();             // prior MFMA reads done (u=0: T5 ready)
        {   // stage Bl[o][k] from tmp row (u32 bf16 pairs, pure bit-copy)
            const unsigned int* tpu = (const unsigned int*)WS + (size_t)bh * 2048;
#pragma unroll
            for (int kk = 0; kk < 4; ++kk) {
                int ky = kg*4 + kk;
                unsigned int g = tpu[ky*64 + o];
                Bl[o*APITCH + ky]      = (unsigned short)(g & 0xffffu);
                Bl[o*APITCH + 32 + ky] = (unsigned short)(g >> 16);
            }
        }
        __syncthreads();
        f32x4 acc[2][4];             // [m-tile][n-tile]
#pragma unroll
        for (int mt = 0; mt < 2; ++mt)
#pragma unroll
            for (int n = 0; n < 4; ++n) acc[mt][n] = (f32x4){0.f,0.f,0.f,0.f};
#pragma unroll
        for (int kk = 0; kk < 2; ++kk) {
            short8 af[2];
#pragma unroll
            for (int mt = 0; mt < 2; ++mt)
                af[mt] = *(const short8*)&T5[(wave*32 + mt*16 + col)*APITCH
                                             + kk*32 + kq*8];
#pragma unroll
            for (int n = 0; n < 4; ++n) {
                short8 bf = *(const short8*)&Bl[(n*16 + col)*APITCH
                                                + kk*32 + kq*8];
#pragma unroll
                for (int mt = 0; mt < 2; ++mt)
                    acc[mt][n] = __builtin_amdgcn_mfma_f32_16x16x32_bf16(
                                     af[mt], bf, acc[mt][n], 0, 0, 0);
            }
        }
        float* R = out + (size_t)bh * 16384;
#pragma unroll
        for (int mt = 0; mt < 2; ++mt)
#pragma unroll
            for (int n = 0; n < 4; ++n)
#pragma unroll
                for (int q = 0; q < 4; ++q) {
                    int w = wave*32 + mt*16 + kq*4 + q;
                    R[w*64 + n*16 + col] = acc[mt][n][q] + bv[n];
                }
    }
}

extern "C" void kernel_launch(void* const* d_in, const int* in_sizes, int n_in,
                              void* d_out, int out_size, void* d_ws, size_t ws_size,
                              hipStream_t stream) {
    (void)in_sizes; (void)n_in; (void)out_size;
    if (ws_size < WS_FLOATS_NEEDED * sizeof(float)) return;  // ws observed = 1 GiB
    const float* x    = (const float*)d_in[0];
    const float* w1re = (const float*)d_in[1];
    const float* w1im = (const float*)d_in[2];
    const float* w2re = (const float*)d_in[3];
    const float* w2im = (const float*)d_in[4];
    const float* bias = (const float*)d_in[5];
    float* O  = (float*)d_out;
    float* WS = (float*)d_ws;

    k1_dft_w <<<1024,  512, 0, stream>>>(x, WS);
    k2_dft_h <<< 512, 1024, 0, stream>>>(WS);
    k3_mix   <<< 256,  512, 0, stream>>>(w1re, w1im, w2re, w2im, WS);
    k4_idft_h<<< 512, 1024, 0, stream>>>(WS);
    k5_idft_w<<<1024,  512, 0, stream>>>(bias, WS, O);
}

// Round 16
// 215.220 us; speedup vs baseline: 1.0918x; 1.0918x over previous
//
#include <hip/hip_runtime.h>
#include <math.h>

#define NB 16
#define NH 256
#define NW 256
#define TWO_PI 6.28318530717958647692f
#define FSCALE (1.0f/65536.0f)       // norm='forward' 1/(H*W)

// Workspace layout (float-sized slots). ws_size = 1 GiB; we use 48 MB.
// All intermediates are bf16 packed as u32 (re | im<<16) — cross-dispatch
// stores are >=4B (r10 lesson: 2-byte WS stores diverge under graph replay).
//   [0, 2^23)        G1u[bh][ky][i] u32 cplx (K1->K2); reused as
//                    tmpu[bh][ky][o] u32 cplx (K4->K5).   stride 2048 u32/bh
//   [2^23, +2^21)    Xu[b][kx][ky][i]  u32 cplx (K2->K3)
//   [2^23+2^21,+2^21) ofu[b][kx][ky][o] u32 cplx (K3->K4)
// r15 lesson: 512-thr k1/k5 restructure regressed (L1 thrash on transposed
// staging) — r13's 256-thr k1/k5 restored verbatim.
#define OFF_X  ((size_t)1 << 23)
#define OFF_OF (((size_t)1 << 23) + ((size_t)1 << 21))
#define WS_FLOATS_NEEDED (((size_t)1 << 23) + ((size_t)2 << 21))

typedef __attribute__((ext_vector_type(8))) short short8;
typedef __attribute__((ext_vector_type(4))) float f32x4;

__device__ __forceinline__ unsigned short f2bf(float f) {
    unsigned int u = __float_as_uint(f);
    unsigned int r = (u + 0x7FFFu + ((u >> 16) & 1u)) >> 16;
    return (unsigned short)r;
}
__device__ __forceinline__ float bf2f(unsigned int u16) {   // u16: low 16 bits
    return __uint_as_float(u16 << 16);
}
__device__ __forceinline__ unsigned int pk2(float a, float b) {
    return (unsigned int)f2bf(a) | ((unsigned int)f2bf(b) << 16);
}

// ---------------- K1: forward DFT over w via bf16 MFMA ----------------------
// A = x^T (M = i), B = T (N = modes: 0-31 cos->re, 32-63 -sin->im).
// 256 thr / 4 waves; thread-per-row staging (best L1 line reuse).
#define XPITCH 264   // ushorts per LDS row (256 + 8 pad)
__global__ __launch_bounds__(256) void k1_dft_w(const float* __restrict__ x,
                                                float* __restrict__ WS) {
    __shared__ float2 tw[256];
    __shared__ unsigned short Al[64 * XPITCH];   // T[mode][w] bf16, 33 KB
    __shared__ unsigned short Xl[64 * XPITCH];   // x^T[i][w] bf16, 33 KB
    int t = threadIdx.x;
    { float s, c; sincosf(TWO_PI * (float)t * (1.0f/256.0f), &s, &c);
      tw[t] = make_float2(c, s); }
    __syncthreads();
    {   // build T from tw: thread t covers m = t>>2, w = (t&3)*64 .. +63
        int m  = t >> 2;
        int w0 = (t & 3) * 64;
        int ky = m & 31;
        for (int dw8 = 0; dw8 < 8; ++dw8) {
            short8 v8;
#pragma unroll
            for (int j = 0; j < 8; ++j) {
                int w = w0 + dw8*8 + j;
                float2 cs = tw[(ky * w) & 255];
                float v = (m < 32) ? cs.x : -cs.y;
                v8[j] = (short)f2bf(v * FSCALE);
            }
            *(short8*)&Al[m * XPITCH + w0 + dw8*8] = v8;
        }
    }
    int wave = t >> 6, lane = t & 63;
    int col = lane & 15, kq = lane >> 4;
    unsigned int* Gu = (unsigned int*)WS;
    for (int u = 0; u < 4; ++u) {
        int bh = blockIdx.x * 4 + u;
        __syncthreads();             // T ready / previous MFMA reads done
        {   // stage x^T: thread t owns w-row t
            const float* xs = x + (size_t)bh * 16384 + t * 64;
            for (int i4 = 0; i4 < 16; ++i4) {
                float4 v = *(const float4*)(xs + i4*4);
                Xl[(i4*4+0)*XPITCH + t] = f2bf(v.x);
                Xl[(i4*4+1)*XPITCH + t] = f2bf(v.y);
                Xl[(i4*4+2)*XPITCH + t] = f2bf(v.z);
                Xl[(i4*4+3)*XPITCH + t] = f2bf(v.w);
            }
        }
        __syncthreads();
        f32x4 acc[4];
#pragma unroll
        for (int n = 0; n < 4; ++n) acc[n] = (f32x4){0.f, 0.f, 0.f, 0.f};
#pragma unroll
        for (int kk = 0; kk < 8; ++kk) {
            int k = kk*32 + kq*8;
            short8 af = *(const short8*)&Xl[(wave*16 + col) * XPITCH + k];
#pragma unroll
            for (int n = 0; n < 4; ++n) {
                short8 bf = *(const short8*)&Al[(n*16 + col) * XPITCH + k];
                acc[n] = __builtin_amdgcn_mfma_f32_16x16x32_bf16(af, bf, acc[n], 0, 0, 0);
            }
        }
        // pack: n=g (re) with n=g+2 (im), ky = g*16+col, i = wave*16+kq*4+q
        int i0 = wave*16 + kq*4;
        unsigned int* gp = Gu + (size_t)bh * 2048;
#pragma unroll
        for (int g = 0; g < 2; ++g) {
            int ky = g*16 + col;
            uint4 pk;
            pk.x = pk2(acc[g][0], acc[g+2][0]);
            pk.y = pk2(acc[g][1], acc[g+2][1]);
            pk.z = pk2(acc[g][2], acc[g+2][2]);
            pk.w = pk2(acc[g][3], acc[g+2][3]);
            *(uint4*)(gp + ky*64 + i0) = pk;
        }
    }
}

// ---------------- K2: forward DFT over h via bf16 MFMA (h-folded, K=256) -----
// Per (b,ky): X_re[64 kx, 64 i] = A2 · [P_re | M_im], X_im = A2 · [P_im | -M_re]
// A2[kx][s]: s<=128: cos(kx*s); s>128: sin(kx*(s-128)).  1024 thr, 16 waves.
#define K2P 264
__global__ __launch_bounds__(1024) void k2_dft_h(float* __restrict__ WS) {
    int b  = blockIdx.x >> 5;
    int ky = blockIdx.x & 31;
    int t  = threadIdx.x;
    __shared__ float2 tw[256];
    __shared__ unsigned short A2l[64 * K2P];     // 33 KB
    __shared__ unsigned short B1l[64 * K2P];
    __shared__ unsigned short B2l[64 * K2P];
    if (t < 256) { float s, c; sincosf(TWO_PI * (float)t * (1.0f/256.0f), &s, &c);
                   tw[t] = make_float2(c, s); }
    __syncthreads();
    {   // build A2 from tw: thread t covers row r = t>>4, s = (t&15)*16 .. +15
        int r = t >> 4, s0 = (t & 15) * 16;
        int kxe = (r < 32) ? r : r + 192;
#pragma unroll
        for (int c8 = 0; c8 < 2; ++c8) {
            short8 v8;
#pragma unroll
            for (int j = 0; j < 8; ++j) {
                int s = s0 + c8*8 + j;
                float v = (s <= 128) ? tw[(kxe * s) & 255].x
                                     : tw[(kxe * (s - 128)) & 255].y;
                v8[j] = (short)f2bf(v);
            }
            *(short8*)&A2l[r*K2P + s0 + c8*8] = v8;
        }
    }
    // stage + fold G (bf16 in, fp32 fold, bf16 store)
    int i = t & 63, hg = t >> 6;     // hg 0..15
    const unsigned int* gu = (const unsigned int*)WS
                             + (size_t)(b*256)*2048 + ky*64 + i;
    for (int s2 = 0; hg + 16*s2 <= 128; ++s2) {
        int hp = hg + 16*s2;
        unsigned int ga = gu[(size_t)hp*2048];
        float are = bf2f(ga & 0xffffu), aim = bf2f(ga >> 16);
        if (hp == 0 || hp == 128) {
            B1l[i*K2P + hp] = f2bf(are);         // P_re = G
            B2l[i*K2P + hp] = f2bf(aim);         // P_im
        } else {
            unsigned int gb = gu[(size_t)(256-hp)*2048];
            float bre = bf2f(gb & 0xffffu), bim = bf2f(gb >> 16);
            B1l[i*K2P + hp]       = f2bf(are + bre);    // P_re
            B1l[i*K2P + 128 + hp] = f2bf(aim - bim);    // M_im
            B2l[i*K2P + hp]       = f2bf(aim + bim);    // P_im
            B2l[i*K2P + 128 + hp] = f2bf(bre - are);    // -M_re
        }
    }
    __syncthreads();
    int wave = t >> 6, col = t & 15, kq = (t >> 4) & 3;
    int mt = wave >> 2, n = wave & 3;    // one (mt,n) pair per wave
    f32x4 ar = (f32x4){0.f,0.f,0.f,0.f}, ai = (f32x4){0.f,0.f,0.f,0.f};
#pragma unroll
    for (int kk = 0; kk < 8; ++kk) {
        int k = kk*32 + kq*8;
        short8 af = *(const short8*)&A2l[(mt*16 + col)*K2P + k];
        short8 b1 = *(const short8*)&B1l[(n*16 + col)*K2P + k];
        short8 b2 = *(const short8*)&B2l[(n*16 + col)*K2P + k];
        ar = __builtin_amdgcn_mfma_f32_16x16x32_bf16(af, b1, ar, 0, 0, 0);
        ai = __builtin_amdgcn_mfma_f32_16x16x32_bf16(af, b2, ai, 0, 0, 0);
    }
    unsigned int* Xu = (unsigned int*)(WS + OFF_X);
#pragma unroll
    for (int q = 0; q < 4; ++q) {
        int kxrow = mt*16 + kq*4 + q;
        Xu[(((size_t)b*64 + kxrow)*32 + ky)*64 + n*16 + col] = pk2(ar[q], ai[q]);
    }
}

// ---------------- K3: channel mixing (complex 64x64 per (kx,ky)) -------------
__global__ __launch_bounds__(512) void k3_mix(const float* __restrict__ w1re,
                                              const float* __restrict__ w1im,
                                              const float* __restrict__ w2re,
                                              const float* __restrict__ w2im,
                                              float* __restrict__ WS) {
    int kx  = blockIdx.x & 63;       // 0..63
    int kyq = blockIdx.x >> 6;       // 0..3; ky = kyq*8 + kyl
    int t   = threadIdx.x;
    __shared__ float2 lx[8192];      // [b][ky8][i] = 64 KB
    __shared__ float  lw[2][2][4][576];  // [buf][re/im][i4][o*9+ky8] = 36 KB
    const float* wre = (kx < 32) ? w1re : w2re;
    const float* wim = (kx < 32) ? w1im : w2im;
    int m = kx & 31;
    const unsigned int* Xu = (const unsigned int*)(WS + OFF_X);
    for (int n = t; n < 8192; n += 512) {
        int bb = n >> 9, ky8 = (n >> 6) & 7, ii = n & 63;
        unsigned int g = Xu[(((size_t)bb*64 + kx)*32 + kyq*8 + ky8)*64 + ii];
        lx[n] = make_float2(bf2f(g & 0xffffu), bf2f(g >> 16));
    }
    int sarr = t & 1, so = (t >> 1) & 63, si4 = t >> 7;
    const float* wsrc = sarr ? wim : wre;
    size_t sbase = (size_t)m*32 + kyq*8;
    int kyl = t >> 6;                // 0..7
    int o   = t & 63;
    int kyg = kyq*8 + kyl;
    float ar[16], ai[16];
#pragma unroll
    for (int bb = 0; bb < 16; ++bb) { ar[bb] = 0.f; ai[bb] = 0.f; }

    float4 wa, wb;
    {
        const float* src = wsrc + ((size_t)(si4*64 + so)*1024 + sbase);
        wa = *(const float4*)src; wb = *(const float4*)(src + 4);
        float* dst = &lw[0][sarr][si4][so*9];
        dst[0]=wa.x; dst[1]=wa.y; dst[2]=wa.z; dst[3]=wa.w;
        dst[4]=wb.x; dst[5]=wb.y; dst[6]=wb.z; dst[7]=wb.w;
    }
    __syncthreads();

    for (int k = 0; k < 16; ++k) {
        int i0 = k*4;
        float4 na, nb;
        if (k < 15) {
            const float* src = wsrc + ((size_t)((i0+4+si4)*64 + so)*1024 + sbase);
            na = *(const float4*)src; nb = *(const float4*)(src + 4);
        }
#pragma unroll
        for (int di = 0; di < 4; ++di) {
            float wr = lw[k & 1][0][di][o*9 + kyl];
            float wi = lw[k & 1][1][di][o*9 + kyl];
            int ii = i0 + di;
#pragma unroll
            for (int bb = 0; bb < 16; ++bb) {
                float2 xv = lx[(bb*8 + kyl)*64 + ii];
                ar[bb] = fmaf(xv.x, wr, fmaf(-xv.y, wi, ar[bb]));
                ai[bb] = fmaf(xv.x, wi, fmaf( xv.y, wr, ai[bb]));
            }
        }
        if (k < 15) {
            float* dst = &lw[(k+1) & 1][sarr][si4][so*9];
            dst[0]=na.x; dst[1]=na.y; dst[2]=na.z; dst[3]=na.w;
            dst[4]=nb.x; dst[5]=nb.y; dst[6]=nb.z; dst[7]=nb.w;
        }
        __syncthreads();
    }
    unsigned int* ofu = (unsigned int*)(WS + OFF_OF);
#pragma unroll
    for (int bb = 0; bb < 16; ++bb) {
        ofu[(((size_t)bb*64 + kx)*32 + kyg)*64 + o] = pk2(ar[bb], ai[bb]);
    }
}

// ---------------- K4: inverse DFT over h via bf16 MFMA (K=128) ---------------
// Per (b,ky): tmp_re[256 h, 64 o] = A4 · [of_re | -of_im],
//             tmp_im = A4 · [of_im | of_re].  A4[h][s]: s<64 cos, s>=64 sin.
// Staging is pure bit-copy (of already bf16; -im = sign-bit XOR).
#define K4P 136
__global__ __launch_bounds__(1024) void k4_idft_h(float* __restrict__ WS) {
    int b  = blockIdx.x >> 5;
    int ky = blockIdx.x & 31;
    int t  = threadIdx.x;
    __shared__ float2 tw[256];
    __shared__ unsigned short A4l[256 * K4P];    // 68 KB
    __shared__ unsigned short B1l[64 * K4P];     // 17 KB
    __shared__ unsigned short B2l[64 * K4P];
    if (t < 256) { float s, c; sincosf(TWO_PI * (float)t * (1.0f/256.0f), &s, &c);
                   tw[t] = make_float2(c, s); }
    __syncthreads();
    {   // build A4 from tw: thread t covers row h = t>>2, s = (t&3)*32 .. +31
        int h = t >> 2, s0 = (t & 3) * 32;
#pragma unroll
        for (int c8 = 0; c8 < 4; ++c8) {
            short8 v8;
#pragma unroll
            for (int j = 0; j < 8; ++j) {
                int s = s0 + c8*8 + j;
                int ds = s & 63;
                int kxe = (ds < 32) ? ds : ds + 192;
                float2 cs = tw[(kxe * h) & 255];
                v8[j] = (short)f2bf((s < 64) ? cs.x : cs.y);
            }
            *(short8*)&A4l[h*K4P + s0 + c8*8] = v8;
        }
    }
    // stage of-slice (u32 bf16 pairs -> bit-copied B tiles)
    int o = t & 63, kg = t >> 6;     // kg 0..15
    const unsigned int* ofu = (const unsigned int*)(WS + OFF_OF);
#pragma unroll
    for (int s = 0; s < 4; ++s) {
        int kx = kg*4 + s;
        unsigned int g = ofu[(((size_t)b*64 + kx)*32 + ky)*64 + o];
        unsigned short lo = (unsigned short)(g & 0xffffu);
        unsigned short hi = (unsigned short)(g >> 16);
        B1l[o*K4P + kx]      = lo;
        B1l[o*K4P + 64 + kx] = hi ^ 0x8000u;     // -im
        B2l[o*K4P + kx]      = hi;
        B2l[o*K4P + 64 + kx] = lo;
    }
    __syncthreads();
    int wave = t >> 6, col = t & 15, kq = (t >> 4) & 3;
    unsigned int* tmpu = (unsigned int*)WS;
#pragma unroll
    for (int e = 0; e < 4; ++e) {
        int p = wave*4 + e, mt = p >> 2, n = p & 3;
        f32x4 ar = (f32x4){0.f,0.f,0.f,0.f}, ai = (f32x4){0.f,0.f,0.f,0.f};
#pragma unroll
        for (int kk = 0; kk < 4; ++kk) {
            int k = kk*32 + kq*8;
            short8 af = *(const short8*)&A4l[(mt*16 + col)*K4P + k];
            short8 b1 = *(const short8*)&B1l[(n*16 + col)*K4P + k];
            short8 b2 = *(const short8*)&B2l[(n*16 + col)*K4P + k];
            ar = __builtin_amdgcn_mfma_f32_16x16x32_bf16(af, b1, ar, 0, 0, 0);
            ai = __builtin_amdgcn_mfma_f32_16x16x32_bf16(af, b2, ai, 0, 0, 0);
        }
#pragma unroll
        for (int q = 0; q < 4; ++q) {
            int h  = mt*16 + kq*4 + q;
            int o2 = n*16 + col;
            tmpu[(size_t)(b*256 + h)*2048 + ky*64 + o2] = pk2(ar[q], ai[q]);
        }
    }
}

// ---------------- K5: inverse rfft over w via bf16 MFMA + bias ---------------
// 256 thr / 4 waves (r13 structure); bias folded into MFMA C-in.
#define APITCH 72
__global__ __launch_bounds__(256) void k5_idft_w(const float* __restrict__ bias,
                                                 const float* __restrict__ WS,
                                                 float* __restrict__ out) {
    int t = threadIdx.x;
    __shared__ float2 tw[256];
    __shared__ unsigned short T5[256 * APITCH];  // [w][k] bf16, 36 KB
    __shared__ unsigned short Bl[64 * APITCH];   // [o][k] bf16, 9 KB
    { float s, c; sincosf(TWO_PI * (float)t * (1.0f/256.0f), &s, &c);
      tw[t] = make_float2(c, s); }
    __syncthreads();
    {   // build T5 row w = t
        int w = t;
#pragma unroll
        for (int ky = 0; ky < 32; ++ky) {
            float2 cs = tw[(ky * w) & 255];
            float sc = ky ? 2.f : 1.f;
            T5[w*APITCH + ky]      = f2bf(sc * cs.x);
            T5[w*APITCH + 32 + ky] = f2bf(-sc * cs.y);
        }
    }
    int o = t & 63, kg = t >> 6;     // staging roles
    int wave = t >> 6, col = t & 15, kq = (t >> 4) & 3;
    float bv[4];
#pragma unroll
    for (int n = 0; n < 4; ++n) bv[n] = bias[n*16 + col];

    for (int u = 0; u < 4; ++u) {
        int bh = blockIdx.x * 4 + u;
        __syncthreads();             // prior MFMA reads done (u=0: T5 ready)
        {   // stage Bl[o][k] from tmp row (u32 bf16 pairs, pure bit-copy)
            const unsigned int* tpu = (const unsigned int*)WS + (size_t)bh * 2048;
#pragma unroll
            for (int kk = 0; kk < 8; ++kk) {
                int ky = kg*8 + kk;
                unsigned int g = tpu[ky*64 + o];
                Bl[o*APITCH + ky]      = (unsigned short)(g & 0xffffu);
                Bl[o*APITCH + 32 + ky] = (unsigned short)(g >> 16);
            }
        }
        __syncthreads();
        f32x4 acc[4][4];             // [m-tile][n-tile], C-in = bias
#pragma unroll
        for (int mt = 0; mt < 4; ++mt)
#pragma unroll
            for (int n = 0; n < 4; ++n)
                acc[mt][n] = (f32x4){bv[n], bv[n], bv[n], bv[n]};
#pragma unroll
        for (int kk = 0; kk < 2; ++kk) {
            short8 af[4];
#pragma unroll
            for (int mt = 0; mt < 4; ++mt)
                af[mt] = *(const short8*)&T5[(wave*64 + mt*16 + col)*APITCH
                                             + kk*32 + kq*8];
#pragma unroll
            for (int n = 0; n < 4; ++n) {
                short8 bf = *(const short8*)&Bl[(n*16 + col)*APITCH
                                                + kk*32 + kq*8];
#pragma unroll
                for (int mt = 0; mt < 4; ++mt)
                    acc[mt][n] = __builtin_amdgcn_mfma_f32_16x16x32_bf16(
                                     af[mt], bf, acc[mt][n], 0, 0, 0);
            }
        }
        float* R = out + (size_t)bh * 16384;
#pragma unroll
        for (int mt = 0; mt < 4; ++mt)
#pragma unroll
            for (int n = 0; n < 4; ++n)
#pragma unroll
                for (int q = 0; q < 4; ++q) {
                    int w = wave*64 + mt*16 + kq*4 + q;
                    R[w*64 + n*16 + col] = acc[mt][n][q];
                }
    }
}

extern "C" void kernel_launch(void* const* d_in, const int* in_sizes, int n_in,
                              void* d_out, int out_size, void* d_ws, size_t ws_size,
                              hipStream_t stream) {
    (void)in_sizes; (void)n_in; (void)out_size;
    if (ws_size < WS_FLOATS_NEEDED * sizeof(float)) return;  // ws observed = 1 GiB
    const float* x    = (const float*)d_in[0];
    const float* w1re = (const float*)d_in[1];
    const float* w1im = (const float*)d_in[2];
    const float* w2re = (const float*)d_in[3];
    const float* w2im = (const float*)d_in[4];
    const float* bias = (const float*)d_in[5];
    float* O  = (float*)d_out;
    float* WS = (float*)d_ws;

    k1_dft_w <<<1024,  256, 0, stream>>>(x, WS);
    k2_dft_h <<< 512, 1024, 0, stream>>>(WS);
    k3_mix   <<< 256,  512, 0, stream>>>(w1re, w1im, w2re, w2im, WS);
    k4_idft_h<<< 512, 1024, 0, stream>>>(WS);
    k5_idft_w<<<1024,  256, 0, stream>>>(bias, WS, O);
}

// Round 17
// 210.711 us; speedup vs baseline: 1.1152x; 1.0214x over previous
//
#include <hip/hip_runtime.h>
#include <math.h>

#define NB 16
#define NH 256
#define NW 256
#define TWO_PI 6.28318530717958647692f
#define FSCALE (1.0f/65536.0f)       // norm='forward' 1/(H*W)

// Workspace layout (float-sized slots). ws_size = 1 GiB; we use 48 MB.
// All intermediates are bf16 packed as u32 (re | im<<16) — cross-dispatch
// stores are >=4B (r10 lesson: 2-byte WS stores diverge under graph replay).
//   [0, 2^23)        G1u[bh][ky][i] u32 cplx (K1->K2); reused as
//                    tmpu[bh][ky][o] u32 cplx (K4->K5).   stride 2048 u32/bh
//   [2^23, +2^21)    Xu[b][kx][ky][i]  u32 cplx (K2->K3)
//   [2^23+2^21,+2^21) ofu[b][kx][ky][o] u32 cplx (K3->K4)
// r16: table-amortization — k1/k5 8 bh/block, k2/k4 2 ky/block (halves
// per-block LDS table rebuild cost; bodies unchanged).
#define OFF_X  ((size_t)1 << 23)
#define OFF_OF (((size_t)1 << 23) + ((size_t)1 << 21))
#define WS_FLOATS_NEEDED (((size_t)1 << 23) + ((size_t)2 << 21))

typedef __attribute__((ext_vector_type(8))) short short8;
typedef __attribute__((ext_vector_type(4))) float f32x4;

__device__ __forceinline__ unsigned short f2bf(float f) {
    unsigned int u = __float_as_uint(f);
    unsigned int r = (u + 0x7FFFu + ((u >> 16) & 1u)) >> 16;
    return (unsigned short)r;
}
__device__ __forceinline__ float bf2f(unsigned int u16) {   // u16: low 16 bits
    return __uint_as_float(u16 << 16);
}
__device__ __forceinline__ unsigned int pk2(float a, float b) {
    return (unsigned int)f2bf(a) | ((unsigned int)f2bf(b) << 16);
}

// ---------------- K1: forward DFT over w via bf16 MFMA ----------------------
// A = x^T (M = i), B = T (N = modes: 0-31 cos->re, 32-63 -sin->im).
// 256 thr / 4 waves; thread-per-row staging; 8 bh per block.
#define XPITCH 264   // ushorts per LDS row (256 + 8 pad)
__global__ __launch_bounds__(256) void k1_dft_w(const float* __restrict__ x,
                                                float* __restrict__ WS) {
    __shared__ float2 tw[256];
    __shared__ unsigned short Al[64 * XPITCH];   // T[mode][w] bf16, 33 KB
    __shared__ unsigned short Xl[64 * XPITCH];   // x^T[i][w] bf16, 33 KB
    int t = threadIdx.x;
    { float s, c; sincosf(TWO_PI * (float)t * (1.0f/256.0f), &s, &c);
      tw[t] = make_float2(c, s); }
    __syncthreads();
    {   // build T from tw: thread t covers m = t>>2, w = (t&3)*64 .. +63
        int m  = t >> 2;
        int w0 = (t & 3) * 64;
        int ky = m & 31;
        for (int dw8 = 0; dw8 < 8; ++dw8) {
            short8 v8;
#pragma unroll
            for (int j = 0; j < 8; ++j) {
                int w = w0 + dw8*8 + j;
                float2 cs = tw[(ky * w) & 255];
                float v = (m < 32) ? cs.x : -cs.y;
                v8[j] = (short)f2bf(v * FSCALE);
            }
            *(short8*)&Al[m * XPITCH + w0 + dw8*8] = v8;
        }
    }
    int wave = t >> 6, lane = t & 63;
    int col = lane & 15, kq = lane >> 4;
    unsigned int* Gu = (unsigned int*)WS;
    for (int u = 0; u < 8; ++u) {
        int bh = blockIdx.x * 8 + u;
        __syncthreads();             // T ready / previous MFMA reads done
        {   // stage x^T: thread t owns w-row t
            const float* xs = x + (size_t)bh * 16384 + t * 64;
            for (int i4 = 0; i4 < 16; ++i4) {
                float4 v = *(const float4*)(xs + i4*4);
                Xl[(i4*4+0)*XPITCH + t] = f2bf(v.x);
                Xl[(i4*4+1)*XPITCH + t] = f2bf(v.y);
                Xl[(i4*4+2)*XPITCH + t] = f2bf(v.z);
                Xl[(i4*4+3)*XPITCH + t] = f2bf(v.w);
            }
        }
        __syncthreads();
        f32x4 acc[4];
#pragma unroll
        for (int n = 0; n < 4; ++n) acc[n] = (f32x4){0.f, 0.f, 0.f, 0.f};
#pragma unroll
        for (int kk = 0; kk < 8; ++kk) {
            int k = kk*32 + kq*8;
            short8 af = *(const short8*)&Xl[(wave*16 + col) * XPITCH + k];
#pragma unroll
            for (int n = 0; n < 4; ++n) {
                short8 bf = *(const short8*)&Al[(n*16 + col) * XPITCH + k];
                acc[n] = __builtin_amdgcn_mfma_f32_16x16x32_bf16(af, bf, acc[n], 0, 0, 0);
            }
        }
        // pack: n=g (re) with n=g+2 (im), ky = g*16+col, i = wave*16+kq*4+q
        int i0 = wave*16 + kq*4;
        unsigned int* gp = Gu + (size_t)bh * 2048;
#pragma unroll
        for (int g = 0; g < 2; ++g) {
            int ky = g*16 + col;
            uint4 pk;
            pk.x = pk2(acc[g][0], acc[g+2][0]);
            pk.y = pk2(acc[g][1], acc[g+2][1]);
            pk.z = pk2(acc[g][2], acc[g+2][2]);
            pk.w = pk2(acc[g][3], acc[g+2][3]);
            *(uint4*)(gp + ky*64 + i0) = pk;
        }
    }
}

// ---------------- K2: forward DFT over h via bf16 MFMA (h-folded, K=256) -----
// Per (b,ky): X_re[64 kx, 64 i] = A2 · [P_re | M_im], X_im = A2 · [P_im | -M_re]
// A2[kx][s]: s<=128: cos(kx*s); s>128: sin(kx*(s-128)).  1024 thr; 2 ky/block.
#define K2P 264
__global__ __launch_bounds__(1024) void k2_dft_h(float* __restrict__ WS) {
    int b   = blockIdx.x >> 4;
    int kyp = blockIdx.x & 15;       // ky = kyp*2 + it
    int t   = threadIdx.x;
    __shared__ float2 tw[256];
    __shared__ unsigned short A2l[64 * K2P];     // 33 KB
    __shared__ unsigned short B1l[64 * K2P];
    __shared__ unsigned short B2l[64 * K2P];
    if (t < 256) { float s, c; sincosf(TWO_PI * (float)t * (1.0f/256.0f), &s, &c);
                   tw[t] = make_float2(c, s); }
    __syncthreads();
    {   // build A2 from tw: thread t covers row r = t>>4, s = (t&15)*16 .. +15
        int r = t >> 4, s0 = (t & 15) * 16;
        int kxe = (r < 32) ? r : r + 192;
#pragma unroll
        for (int c8 = 0; c8 < 2; ++c8) {
            short8 v8;
#pragma unroll
            for (int j = 0; j < 8; ++j) {
                int s = s0 + c8*8 + j;
                float v = (s <= 128) ? tw[(kxe * s) & 255].x
                                     : tw[(kxe * (s - 128)) & 255].y;
                v8[j] = (short)f2bf(v);
            }
            *(short8*)&A2l[r*K2P + s0 + c8*8] = v8;
        }
    }
    int i = t & 63, hg = t >> 6;     // hg 0..15
    int wave = t >> 6, col = t & 15, kq = (t >> 4) & 3;
    int mt = wave >> 2, n = wave & 3;    // one (mt,n) pair per wave
    unsigned int* Xu = (unsigned int*)(WS + OFF_X);
    for (int it = 0; it < 2; ++it) {
        int ky = kyp*2 + it;
        if (it) __syncthreads();     // prior MFMA reads of B tiles done
        // stage + fold G (bf16 in, fp32 fold, bf16 store)
        const unsigned int* gu = (const unsigned int*)WS
                                 + (size_t)(b*256)*2048 + ky*64 + i;
        for (int s2 = 0; hg + 16*s2 <= 128; ++s2) {
            int hp = hg + 16*s2;
            unsigned int ga = gu[(size_t)hp*2048];
            float are = bf2f(ga & 0xffffu), aim = bf2f(ga >> 16);
            if (hp == 0 || hp == 128) {
                B1l[i*K2P + hp] = f2bf(are);         // P_re = G
                B2l[i*K2P + hp] = f2bf(aim);         // P_im
            } else {
                unsigned int gb = gu[(size_t)(256-hp)*2048];
                float bre = bf2f(gb & 0xffffu), bim = bf2f(gb >> 16);
                B1l[i*K2P + hp]       = f2bf(are + bre);    // P_re
                B1l[i*K2P + 128 + hp] = f2bf(aim - bim);    // M_im
                B2l[i*K2P + hp]       = f2bf(aim + bim);    // P_im
                B2l[i*K2P + 128 + hp] = f2bf(bre - are);    // -M_re
            }
        }
        __syncthreads();
        f32x4 ar = (f32x4){0.f,0.f,0.f,0.f}, ai = (f32x4){0.f,0.f,0.f,0.f};
#pragma unroll
        for (int kk = 0; kk < 8; ++kk) {
            int k = kk*32 + kq*8;
            short8 af = *(const short8*)&A2l[(mt*16 + col)*K2P + k];
            short8 b1 = *(const short8*)&B1l[(n*16 + col)*K2P + k];
            short8 b2 = *(const short8*)&B2l[(n*16 + col)*K2P + k];
            ar = __builtin_amdgcn_mfma_f32_16x16x32_bf16(af, b1, ar, 0, 0, 0);
            ai = __builtin_amdgcn_mfma_f32_16x16x32_bf16(af, b2, ai, 0, 0, 0);
        }
#pragma unroll
        for (int q = 0; q < 4; ++q) {
            int kxrow = mt*16 + kq*4 + q;
            Xu[(((size_t)b*64 + kxrow)*32 + ky)*64 + n*16 + col]
                = pk2(ar[q], ai[q]);
        }
    }
}

// ---------------- K3: channel mixing (complex 64x64 per (kx,ky)) -------------
__global__ __launch_bounds__(512) void k3_mix(const float* __restrict__ w1re,
                                              const float* __restrict__ w1im,
                                              const float* __restrict__ w2re,
                                              const float* __restrict__ w2im,
                                              float* __restrict__ WS) {
    int kx  = blockIdx.x & 63;       // 0..63
    int kyq = blockIdx.x >> 6;       // 0..3; ky = kyq*8 + kyl
    int t   = threadIdx.x;
    __shared__ float2 lx[8192];      // [b][ky8][i] = 64 KB
    __shared__ float  lw[2][2][4][576];  // [buf][re/im][i4][o*9+ky8] = 36 KB
    const float* wre = (kx < 32) ? w1re : w2re;
    const float* wim = (kx < 32) ? w1im : w2im;
    int m = kx & 31;
    const unsigned int* Xu = (const unsigned int*)(WS + OFF_X);
    for (int n = t; n < 8192; n += 512) {
        int bb = n >> 9, ky8 = (n >> 6) & 7, ii = n & 63;
        unsigned int g = Xu[(((size_t)bb*64 + kx)*32 + kyq*8 + ky8)*64 + ii];
        lx[n] = make_float2(bf2f(g & 0xffffu), bf2f(g >> 16));
    }
    int sarr = t & 1, so = (t >> 1) & 63, si4 = t >> 7;
    const float* wsrc = sarr ? wim : wre;
    size_t sbase = (size_t)m*32 + kyq*8;
    int kyl = t >> 6;                // 0..7
    int o   = t & 63;
    int kyg = kyq*8 + kyl;
    float ar[16], ai[16];
#pragma unroll
    for (int bb = 0; bb < 16; ++bb) { ar[bb] = 0.f; ai[bb] = 0.f; }

    float4 wa, wb;
    {
        const float* src = wsrc + ((size_t)(si4*64 + so)*1024 + sbase);
        wa = *(const float4*)src; wb = *(const float4*)(src + 4);
        float* dst = &lw[0][sarr][si4][so*9];
        dst[0]=wa.x; dst[1]=wa.y; dst[2]=wa.z; dst[3]=wa.w;
        dst[4]=wb.x; dst[5]=wb.y; dst[6]=wb.z; dst[7]=wb.w;
    }
    __syncthreads();

    for (int k = 0; k < 16; ++k) {
        int i0 = k*4;
        float4 na, nb;
        if (k < 15) {
            const float* src = wsrc + ((size_t)((i0+4+si4)*64 + so)*1024 + sbase);
            na = *(const float4*)src; nb = *(const float4*)(src + 4);
        }
#pragma unroll
        for (int di = 0; di < 4; ++di) {
            float wr = lw[k & 1][0][di][o*9 + kyl];
            float wi = lw[k & 1][1][di][o*9 + kyl];
            int ii = i0 + di;
#pragma unroll
            for (int bb = 0; bb < 16; ++bb) {
                float2 xv = lx[(bb*8 + kyl)*64 + ii];
                ar[bb] = fmaf(xv.x, wr, fmaf(-xv.y, wi, ar[bb]));
                ai[bb] = fmaf(xv.x, wi, fmaf( xv.y, wr, ai[bb]));
            }
        }
        if (k < 15) {
            float* dst = &lw[(k+1) & 1][sarr][si4][so*9];
            dst[0]=na.x; dst[1]=na.y; dst[2]=na.z; dst[3]=na.w;
            dst[4]=nb.x; dst[5]=nb.y; dst[6]=nb.z; dst[7]=nb.w;
        }
        __syncthreads();
    }
    unsigned int* ofu = (unsigned int*)(WS + OFF_OF);
#pragma unroll
    for (int bb = 0; bb < 16; ++bb) {
        ofu[(((size_t)bb*64 + kx)*32 + kyg)*64 + o] = pk2(ar[bb], ai[bb]);
    }
}

// ---------------- K4: inverse DFT over h via bf16 MFMA (K=128) ---------------
// Per (b,ky): tmp_re[256 h, 64 o] = A4 · [of_re | -of_im],
//             tmp_im = A4 · [of_im | of_re].  A4[h][s]: s<64 cos, s>=64 sin.
// Staging is pure bit-copy; 2 ky per block.
#define K4P 136
__global__ __launch_bounds__(1024) void k4_idft_h(float* __restrict__ WS) {
    int b   = blockIdx.x >> 4;
    int kyp = blockIdx.x & 15;       // ky = kyp*2 + it
    int t   = threadIdx.x;
    __shared__ float2 tw[256];
    __shared__ unsigned short A4l[256 * K4P];    // 68 KB
    __shared__ unsigned short B1l[64 * K4P];     // 17 KB
    __shared__ unsigned short B2l[64 * K4P];
    if (t < 256) { float s, c; sincosf(TWO_PI * (float)t * (1.0f/256.0f), &s, &c);
                   tw[t] = make_float2(c, s); }
    __syncthreads();
    {   // build A4 from tw: thread t covers row h = t>>2, s = (t&3)*32 .. +31
        int h = t >> 2, s0 = (t & 3) * 32;
#pragma unroll
        for (int c8 = 0; c8 < 4; ++c8) {
            short8 v8;
#pragma unroll
            for (int j = 0; j < 8; ++j) {
                int s = s0 + c8*8 + j;
                int ds = s & 63;
                int kxe = (ds < 32) ? ds : ds + 192;
                float2 cs = tw[(kxe * h) & 255];
                v8[j] = (short)f2bf((s < 64) ? cs.x : cs.y);
            }
            *(short8*)&A4l[h*K4P + s0 + c8*8] = v8;
        }
    }
    int o = t & 63, kg = t >> 6;     // kg 0..15
    int wave = t >> 6, col = t & 15, kq = (t >> 4) & 3;
    const unsigned int* ofu = (const unsigned int*)(WS + OFF_OF);
    unsigned int* tmpu = (unsigned int*)WS;
    for (int it = 0; it < 2; ++it) {
        int ky = kyp*2 + it;
        if (it) __syncthreads();     // prior MFMA reads of B tiles done
        // stage of-slice (u32 bf16 pairs -> bit-copied B tiles)
#pragma unroll
        for (int s = 0; s < 4; ++s) {
            int kx = kg*4 + s;
            unsigned int g = ofu[(((size_t)b*64 + kx)*32 + ky)*64 + o];
            unsigned short lo = (unsigned short)(g & 0xffffu);
            unsigned short hi = (unsigned short)(g >> 16);
            B1l[o*K4P + kx]      = lo;
            B1l[o*K4P + 64 + kx] = hi ^ 0x8000u;     // -im
            B2l[o*K4P + kx]      = hi;
            B2l[o*K4P + 64 + kx] = lo;
        }
        __syncthreads();
#pragma unroll
        for (int e = 0; e < 4; ++e) {
            int p = wave*4 + e, mt = p >> 2, n = p & 3;
            f32x4 ar = (f32x4){0.f,0.f,0.f,0.f}, ai = (f32x4){0.f,0.f,0.f,0.f};
#pragma unroll
            for (int kk = 0; kk < 4; ++kk) {
                int k = kk*32 + kq*8;
                short8 af = *(const short8*)&A4l[(mt*16 + col)*K4P + k];
                short8 b1 = *(const short8*)&B1l[(n*16 + col)*K4P + k];
                short8 b2 = *(const short8*)&B2l[(n*16 + col)*K4P + k];
                ar = __builtin_amdgcn_mfma_f32_16x16x32_bf16(af, b1, ar, 0, 0, 0);
                ai = __builtin_amdgcn_mfma_f32_16x16x32_bf16(af, b2, ai, 0, 0, 0);
            }
#pragma unroll
            for (int q = 0; q < 4; ++q) {
                int h  = mt*16 + kq*4 + q;
                int o2 = n*16 + col;
                tmpu[(size_t)(b*256 + h)*2048 + ky*64 + o2] = pk2(ar[q], ai[q]);
            }
        }
    }
}

// ---------------- K5: inverse rfft over w via bf16 MFMA + bias ---------------
// 256 thr / 4 waves; bias folded into MFMA C-in; 8 bh per block.
#define APITCH 72
__global__ __launch_bounds__(256) void k5_idft_w(const float* __restrict__ bias,
                                                 const float* __restrict__ WS,
                                                 float* __restrict__ out) {
    int t = threadIdx.x;
    __shared__ float2 tw[256];
    __shared__ unsigned short T5[256 * APITCH];  // [w][k] bf16, 36 KB
    __shared__ unsigned short Bl[64 * APITCH];   // [o][k] bf16, 9 KB
    { float s, c; sincosf(TWO_PI * (float)t * (1.0f/256.0f), &s, &c);
      tw[t] = make_float2(c, s); }
    __syncthreads();
    {   // build T5 row w = t
        int w = t;
#pragma unroll
        for (int ky = 0; ky < 32; ++ky) {
            float2 cs = tw[(ky * w) & 255];
            float sc = ky ? 2.f : 1.f;
            T5[w*APITCH + ky]      = f2bf(sc * cs.x);
            T5[w*APITCH + 32 + ky] = f2bf(-sc * cs.y);
        }
    }
    int o = t & 63, kg = t >> 6;     // staging roles
    int wave = t >> 6, col = t & 15, kq = (t >> 4) & 3;
    float bv[4];
#pragma unroll
    for (int n = 0; n < 4; ++n) bv[n] = bias[n*16 + col];

    for (int u = 0; u < 8; ++u) {
        int bh = blockIdx.x * 8 + u;
        __syncthreads();             // prior MFMA reads done (u=0: T5 ready)
        {   // stage Bl[o][k] from tmp row (u32 bf16 pairs, pure bit-copy)
            const unsigned int* tpu = (const unsigned int*)WS + (size_t)bh * 2048;
#pragma unroll
            for (int kk = 0; kk < 8; ++kk) {
                int ky = kg*8 + kk;
                unsigned int g = tpu[ky*64 + o];
                Bl[o*APITCH + ky]      = (unsigned short)(g & 0xffffu);
                Bl[o*APITCH + 32 + ky] = (unsigned short)(g >> 16);
            }
        }
        __syncthreads();
        f32x4 acc[4][4];             // [m-tile][n-tile], C-in = bias
#pragma unroll
        for (int mt = 0; mt < 4; ++mt)
#pragma unroll
            for (int n = 0; n < 4; ++n)
                acc[mt][n] = (f32x4){bv[n], bv[n], bv[n], bv[n]};
#pragma unroll
        for (int kk = 0; kk < 2; ++kk) {
            short8 af[4];
#pragma unroll
            for (int mt = 0; mt < 4; ++mt)
                af[mt] = *(const short8*)&T5[(wave*64 + mt*16 + col)*APITCH
                                             + kk*32 + kq*8];
#pragma unroll
            for (int n = 0; n < 4; ++n) {
                short8 bf = *(const short8*)&Bl[(n*16 + col)*APITCH
                                                + kk*32 + kq*8];
#pragma unroll
                for (int mt = 0; mt < 4; ++mt)
                    acc[mt][n] = __builtin_amdgcn_mfma_f32_16x16x32_bf16(
                                     af[mt], bf, acc[mt][n], 0, 0, 0);
            }
        }
        float* R = out + (size_t)bh * 16384;
#pragma unroll
        for (int mt = 0; mt < 4; ++mt)
#pragma unroll
            for (int n = 0; n < 4; ++n)
#pragma unroll
                for (int q = 0; q < 4; ++q) {
                    int w = wave*64 + mt*16 + kq*4 + q;
                    R[w*64 + n*16 + col] = acc[mt][n][q];
                }
    }
}

extern "C" void kernel_launch(void* const* d_in, const int* in_sizes, int n_in,
                              void* d_out, int out_size, void* d_ws, size_t ws_size,
                              hipStream_t stream) {
    (void)in_sizes; (void)n_in; (void)out_size;
    if (ws_size < WS_FLOATS_NEEDED * sizeof(float)) return;  // ws observed = 1 GiB
    const float* x    = (const float*)d_in[0];
    const float* w1re = (const float*)d_in[1];
    const float* w1im = (const float*)d_in[2];
    const float* w2re = (const float*)d_in[3];
    const float* w2im = (const float*)d_in[4];
    const float* bias = (const float*)d_in[5];
    float* O  = (float*)d_out;
    float* WS = (float*)d_ws;

    k1_dft_w <<< 512,  256, 0, stream>>>(x, WS);
    k2_dft_h <<< 256, 1024, 0, stream>>>(WS);
    k3_mix   <<< 256,  512, 0, stream>>>(w1re, w1im, w2re, w2im, WS);
    k4_idft_h<<< 256, 1024, 0, stream>>>(WS);
    k5_idft_w<<< 512,  256, 0, stream>>>(bias, WS, O);
}

// Round 18
// 209.656 us; speedup vs baseline: 1.1208x; 1.0050x over previous
//
#include <hip/hip_runtime.h>
#include <math.h>

#define NB 16
#define NH 256
#define NW 256
#define TWO_PI 6.28318530717958647692f
#define FSCALE (1.0f/65536.0f)       // norm='forward' 1/(H*W)

// Workspace layout (float-sized slots). ws_size = 1 GiB; we use 48 MB.
// All intermediates are bf16 packed as u32 (re | im<<16) — cross-dispatch
// stores are >=4B (r10 lesson: 2-byte WS stores diverge under graph replay).
//   [0, 2^23)        G1u[bh][ky][i] u32 cplx (K1->K2); reused as
//                    tmpu[bh][ky][o] u32 cplx (K4->K5).   stride 2048 u32/bh
//   [2^23, +2^21)    Xu[b][kx][ky][i]  u32 cplx (K2->K3)
//   [2^23+2^21,+2^21) ofu[b][kx][ky][o] u32 cplx (K3->K4)
// r18: k1 -> 512 thr (4 waves/SIMD) with row-contiguous staging; MFMA split
// and packed store reuse the r15-validated pattern. Everything else = r17.
#define OFF_X  ((size_t)1 << 23)
#define OFF_OF (((size_t)1 << 23) + ((size_t)1 << 21))
#define WS_FLOATS_NEEDED (((size_t)1 << 23) + ((size_t)2 << 21))

typedef __attribute__((ext_vector_type(8))) short short8;
typedef __attribute__((ext_vector_type(4))) float f32x4;

__device__ __forceinline__ unsigned short f2bf(float f) {
    unsigned int u = __float_as_uint(f);
    unsigned int r = (u + 0x7FFFu + ((u >> 16) & 1u)) >> 16;
    return (unsigned short)r;
}
__device__ __forceinline__ float bf2f(unsigned int u16) {   // u16: low 16 bits
    return __uint_as_float(u16 << 16);
}
__device__ __forceinline__ unsigned int pk2(float a, float b) {
    return (unsigned int)f2bf(a) | ((unsigned int)f2bf(b) << 16);
}

// ---------------- K1: forward DFT over w via bf16 MFMA ----------------------
// A = x^T (M = i), B = T (N = modes: 0-31 cos->re, 32-63 -sin->im).
// 512 thr / 8 waves; thread t stages w-row t>>1, i-half (t&1)*32 (wave reads
// 8 KB contiguous); wave = (mtile = wave&3, g = wave>>2) computes n-tiles
// {g, g+2}; 8 bh per block.
#define XPITCH 264   // ushorts per LDS row (256 + 8 pad)
__global__ __launch_bounds__(512) void k1_dft_w(const float* __restrict__ x,
                                                float* __restrict__ WS) {
    __shared__ float2 tw[256];
    __shared__ unsigned short Al[64 * XPITCH];   // T[mode][w] bf16, 33 KB
    __shared__ unsigned short Xl[64 * XPITCH];   // x^T[i][w] bf16, 33 KB
    int t = threadIdx.x;
    if (t < 256) { float s, c; sincosf(TWO_PI * (float)t * (1.0f/256.0f), &s, &c);
                   tw[t] = make_float2(c, s); }
    __syncthreads();
    {   // build T from tw: thread t covers m = t>>3, w = (t&7)*32 .. +31
        int m = t >> 3, w0T = (t & 7) * 32;
        int ky = m & 31;
#pragma unroll
        for (int d8 = 0; d8 < 4; ++d8) {
            short8 v8;
#pragma unroll
            for (int j = 0; j < 8; ++j) {
                int w = w0T + d8*8 + j;
                float2 cs = tw[(ky * w) & 255];
                float v = (m < 32) ? cs.x : -cs.y;
                v8[j] = (short)f2bf(v * FSCALE);
            }
            *(short8*)&Al[m * XPITCH + w0T + d8*8] = v8;
        }
    }
    int wave = t >> 6, lane = t & 63;
    int col = lane & 15, kq = lane >> 4;         // kq 0..3
    int mtile = wave & 3, g = wave >> 2;
    int wrow = t >> 1, ihalf = (t & 1) * 32;
    unsigned int* Gu = (unsigned int*)WS;
    for (int u = 0; u < 8; ++u) {
        int bh = blockIdx.x * 8 + u;
        __syncthreads();             // T ready / previous MFMA reads done
        {   // stage x^T: thread t owns w-row t>>1, i-half (t&1)*32
            const float* xs = x + (size_t)bh * 16384 + wrow * 64 + ihalf;
#pragma unroll
            for (int i8 = 0; i8 < 8; ++i8) {
                float4 v = *(const float4*)(xs + i8*4);
                Xl[(ihalf + i8*4 + 0)*XPITCH + wrow] = f2bf(v.x);
                Xl[(ihalf + i8*4 + 1)*XPITCH + wrow] = f2bf(v.y);
                Xl[(ihalf + i8*4 + 2)*XPITCH + wrow] = f2bf(v.z);
                Xl[(ihalf + i8*4 + 3)*XPITCH + wrow] = f2bf(v.w);
            }
        }
        __syncthreads();
        f32x4 a0 = (f32x4){0.f,0.f,0.f,0.f};
        f32x4 a1 = (f32x4){0.f,0.f,0.f,0.f};
#pragma unroll
        for (int kk = 0; kk < 8; ++kk) {
            int k = kk*32 + kq*8;
            short8 af = *(const short8*)&Xl[(mtile*16 + col) * XPITCH + k];
            short8 b0 = *(const short8*)&Al[(g*16 + col) * XPITCH + k];
            short8 b1 = *(const short8*)&Al[((g+2)*16 + col) * XPITCH + k];
            a0 = __builtin_amdgcn_mfma_f32_16x16x32_bf16(af, b0, a0, 0, 0, 0);
            a1 = __builtin_amdgcn_mfma_f32_16x16x32_bf16(af, b1, a1, 0, 0, 0);
        }
        int i0s = mtile*16 + kq*4;
        int ky = g*16 + col;
        uint4 pk;
        pk.x = pk2(a0[0], a1[0]);
        pk.y = pk2(a0[1], a1[1]);
        pk.z = pk2(a0[2], a1[2]);
        pk.w = pk2(a0[3], a1[3]);
        *(uint4*)(Gu + (size_t)bh * 2048 + ky*64 + i0s) = pk;
    }
}

// ---------------- K2: forward DFT over h via bf16 MFMA (h-folded, K=256) -----
// Per (b,ky): X_re[64 kx, 64 i] = A2 · [P_re | M_im], X_im = A2 · [P_im | -M_re]
// A2[kx][s]: s<=128: cos(kx*s); s>128: sin(kx*(s-128)).  1024 thr; 2 ky/block.
#define K2P 264
__global__ __launch_bounds__(1024) void k2_dft_h(float* __restrict__ WS) {
    int b   = blockIdx.x >> 4;
    int kyp = blockIdx.x & 15;       // ky = kyp*2 + it
    int t   = threadIdx.x;
    __shared__ float2 tw[256];
    __shared__ unsigned short A2l[64 * K2P];     // 33 KB
    __shared__ unsigned short B1l[64 * K2P];
    __shared__ unsigned short B2l[64 * K2P];
    if (t < 256) { float s, c; sincosf(TWO_PI * (float)t * (1.0f/256.0f), &s, &c);
                   tw[t] = make_float2(c, s); }
    __syncthreads();
    {   // build A2 from tw: thread t covers row r = t>>4, s = (t&15)*16 .. +15
        int r = t >> 4, s0 = (t & 15) * 16;
        int kxe = (r < 32) ? r : r + 192;
#pragma unroll
        for (int c8 = 0; c8 < 2; ++c8) {
            short8 v8;
#pragma unroll
            for (int j = 0; j < 8; ++j) {
                int s = s0 + c8*8 + j;
                float v = (s <= 128) ? tw[(kxe * s) & 255].x
                                     : tw[(kxe * (s - 128)) & 255].y;
                v8[j] = (short)f2bf(v);
            }
            *(short8*)&A2l[r*K2P + s0 + c8*8] = v8;
        }
    }
    int i = t & 63, hg = t >> 6;     // hg 0..15
    int wave = t >> 6, col = t & 15, kq = (t >> 4) & 3;
    int mt = wave >> 2, n = wave & 3;    // one (mt,n) pair per wave
    unsigned int* Xu = (unsigned int*)(WS + OFF_X);
    for (int it = 0; it < 2; ++it) {
        int ky = kyp*2 + it;
        if (it) __syncthreads();     // prior MFMA reads of B tiles done
        // stage + fold G (bf16 in, fp32 fold, bf16 store)
        const unsigned int* gu = (const unsigned int*)WS
                                 + (size_t)(b*256)*2048 + ky*64 + i;
        for (int s2 = 0; hg + 16*s2 <= 128; ++s2) {
            int hp = hg + 16*s2;
            unsigned int ga = gu[(size_t)hp*2048];
            float are = bf2f(ga & 0xffffu), aim = bf2f(ga >> 16);
            if (hp == 0 || hp == 128) {
                B1l[i*K2P + hp] = f2bf(are);         // P_re = G
                B2l[i*K2P + hp] = f2bf(aim);         // P_im
            } else {
                unsigned int gb = gu[(size_t)(256-hp)*2048];
                float bre = bf2f(gb & 0xffffu), bim = bf2f(gb >> 16);
                B1l[i*K2P + hp]       = f2bf(are + bre);    // P_re
                B1l[i*K2P + 128 + hp] = f2bf(aim - bim);    // M_im
                B2l[i*K2P + hp]       = f2bf(aim + bim);    // P_im
                B2l[i*K2P + 128 + hp] = f2bf(bre - are);    // -M_re
            }
        }
        __syncthreads();
        f32x4 ar = (f32x4){0.f,0.f,0.f,0.f}, ai = (f32x4){0.f,0.f,0.f,0.f};
#pragma unroll
        for (int kk = 0; kk < 8; ++kk) {
            int k = kk*32 + kq*8;
            short8 af = *(const short8*)&A2l[(mt*16 + col)*K2P + k];
            short8 b1 = *(const short8*)&B1l[(n*16 + col)*K2P + k];
            short8 b2 = *(const short8*)&B2l[(n*16 + col)*K2P + k];
            ar = __builtin_amdgcn_mfma_f32_16x16x32_bf16(af, b1, ar, 0, 0, 0);
            ai = __builtin_amdgcn_mfma_f32_16x16x32_bf16(af, b2, ai, 0, 0, 0);
        }
#pragma unroll
        for (int q = 0; q < 4; ++q) {
            int kxrow = mt*16 + kq*4 + q;
            Xu[(((size_t)b*64 + kxrow)*32 + ky)*64 + n*16 + col]
                = pk2(ar[q], ai[q]);
        }
    }
}

// ---------------- K3: channel mixing (complex 64x64 per (kx,ky)) -------------
__global__ __launch_bounds__(512) void k3_mix(const float* __restrict__ w1re,
                                              const float* __restrict__ w1im,
                                              const float* __restrict__ w2re,
                                              const float* __restrict__ w2im,
                                              float* __restrict__ WS) {
    int kx  = blockIdx.x & 63;       // 0..63
    int kyq = blockIdx.x >> 6;       // 0..3; ky = kyq*8 + kyl
    int t   = threadIdx.x;
    __shared__ float2 lx[8192];      // [b][ky8][i] = 64 KB
    __shared__ float  lw[2][2][4][576];  // [buf][re/im][i4][o*9+ky8] = 36 KB
    const float* wre = (kx < 32) ? w1re : w2re;
    const float* wim = (kx < 32) ? w1im : w2im;
    int m = kx & 31;
    const unsigned int* Xu = (const unsigned int*)(WS + OFF_X);
    for (int n = t; n < 8192; n += 512) {
        int bb = n >> 9, ky8 = (n >> 6) & 7, ii = n & 63;
        unsigned int g = Xu[(((size_t)bb*64 + kx)*32 + kyq*8 + ky8)*64 + ii];
        lx[n] = make_float2(bf2f(g & 0xffffu), bf2f(g >> 16));
    }
    int sarr = t & 1, so = (t >> 1) & 63, si4 = t >> 7;
    const float* wsrc = sarr ? wim : wre;
    size_t sbase = (size_t)m*32 + kyq*8;
    int kyl = t >> 6;                // 0..7
    int o   = t & 63;
    int kyg = kyq*8 + kyl;
    float ar[16], ai[16];
#pragma unroll
    for (int bb = 0; bb < 16; ++bb) { ar[bb] = 0.f; ai[bb] = 0.f; }

    float4 wa, wb;
    {
        const float* src = wsrc + ((size_t)(si4*64 + so)*1024 + sbase);
        wa = *(const float4*)src; wb = *(const float4*)(src + 4);
        float* dst = &lw[0][sarr][si4][so*9];
        dst[0]=wa.x; dst[1]=wa.y; dst[2]=wa.z; dst[3]=wa.w;
        dst[4]=wb.x; dst[5]=wb.y; dst[6]=wb.z; dst[7]=wb.w;
    }
    __syncthreads();

    for (int k = 0; k < 16; ++k) {
        int i0 = k*4;
        float4 na, nb;
        if (k < 15) {
            const float* src = wsrc + ((size_t)((i0+4+si4)*64 + so)*1024 + sbase);
            na = *(const float4*)src; nb = *(const float4*)(src + 4);
        }
#pragma unroll
        for (int di = 0; di < 4; ++di) {
            float wr = lw[k & 1][0][di][o*9 + kyl];
            float wi = lw[k & 1][1][di][o*9 + kyl];
            int ii = i0 + di;
#pragma unroll
            for (int bb = 0; bb < 16; ++bb) {
                float2 xv = lx[(bb*8 + kyl)*64 + ii];
                ar[bb] = fmaf(xv.x, wr, fmaf(-xv.y, wi, ar[bb]));
                ai[bb] = fmaf(xv.x, wi, fmaf( xv.y, wr, ai[bb]));
            }
        }
        if (k < 15) {
            float* dst = &lw[(k+1) & 1][sarr][si4][so*9];
            dst[0]=na.x; dst[1]=na.y; dst[2]=na.z; dst[3]=na.w;
            dst[4]=nb.x; dst[5]=nb.y; dst[6]=nb.z; dst[7]=nb.w;
        }
        __syncthreads();
    }
    unsigned int* ofu = (unsigned int*)(WS + OFF_OF);
#pragma unroll
    for (int bb = 0; bb < 16; ++bb) {
        ofu[(((size_t)bb*64 + kx)*32 + kyg)*64 + o] = pk2(ar[bb], ai[bb]);
    }
}

// ---------------- K4: inverse DFT over h via bf16 MFMA (K=128) ---------------
// Per (b,ky): tmp_re[256 h, 64 o] = A4 · [of_re | -of_im],
//             tmp_im = A4 · [of_im | of_re].  A4[h][s]: s<64 cos, s>=64 sin.
// Staging is pure bit-copy; 2 ky per block.
#define K4P 136
__global__ __launch_bounds__(1024) void k4_idft_h(float* __restrict__ WS) {
    int b   = blockIdx.x >> 4;
    int kyp = blockIdx.x & 15;       // ky = kyp*2 + it
    int t   = threadIdx.x;
    __shared__ float2 tw[256];
    __shared__ unsigned short A4l[256 * K4P];    // 68 KB
    __shared__ unsigned short B1l[64 * K4P];     // 17 KB
    __shared__ unsigned short B2l[64 * K4P];
    if (t < 256) { float s, c; sincosf(TWO_PI * (float)t * (1.0f/256.0f), &s, &c);
                   tw[t] = make_float2(c, s); }
    __syncthreads();
    {   // build A4 from tw: thread t covers row h = t>>2, s = (t&3)*32 .. +31
        int h = t >> 2, s0 = (t & 3) * 32;
#pragma unroll
        for (int c8 = 0; c8 < 4; ++c8) {
            short8 v8;
#pragma unroll
            for (int j = 0; j < 8; ++j) {
                int s = s0 + c8*8 + j;
                int ds = s & 63;
                int kxe = (ds < 32) ? ds : ds + 192;
                float2 cs = tw[(kxe * h) & 255];
                v8[j] = (short)f2bf((s < 64) ? cs.x : cs.y);
            }
            *(short8*)&A4l[h*K4P + s0 + c8*8] = v8;
        }
    }
    int o = t & 63, kg = t >> 6;     // kg 0..15
    int wave = t >> 6, col = t & 15, kq = (t >> 4) & 3;
    const unsigned int* ofu = (const unsigned int*)(WS + OFF_OF);
    unsigned int* tmpu = (unsigned int*)WS;
    for (int it = 0; it < 2; ++it) {
        int ky = kyp*2 + it;
        if (it) __syncthreads();     // prior MFMA reads of B tiles done
        // stage of-slice (u32 bf16 pairs -> bit-copied B tiles)
#pragma unroll
        for (int s = 0; s < 4; ++s) {
            int kx = kg*4 + s;
            unsigned int g = ofu[(((size_t)b*64 + kx)*32 + ky)*64 + o];
            unsigned short lo = (unsigned short)(g & 0xffffu);
            unsigned short hi = (unsigned short)(g >> 16);
            B1l[o*K4P + kx]      = lo;
            B1l[o*K4P + 64 + kx] = hi ^ 0x8000u;     // -im
            B2l[o*K4P + kx]      = hi;
            B2l[o*K4P + 64 + kx] = lo;
        }
        __syncthreads();
#pragma unroll
        for (int e = 0; e < 4; ++e) {
            int p = wave*4 + e, mt = p >> 2, n = p & 3;
            f32x4 ar = (f32x4){0.f,0.f,0.f,0.f}, ai = (f32x4){0.f,0.f,0.f,0.f};
#pragma unroll
            for (int kk = 0; kk < 4; ++kk) {
                int k = kk*32 + kq*8;
                short8 af = *(const short8*)&A4l[(mt*16 + col)*K4P + k];
                short8 b1 = *(const short8*)&B1l[(n*16 + col)*K4P + k];
                short8 b2 = *(const short8*)&B2l[(n*16 + col)*K4P + k];
                ar = __builtin_amdgcn_mfma_f32_16x16x32_bf16(af, b1, ar, 0, 0, 0);
                ai = __builtin_amdgcn_mfma_f32_16x16x32_bf16(af, b2, ai, 0, 0, 0);
            }
#pragma unroll
            for (int q = 0; q < 4; ++q) {
                int h  = mt*16 + kq*4 + q;
                int o2 = n*16 + col;
                tmpu[(size_t)(b*256 + h)*2048 + ky*64 + o2] = pk2(ar[q], ai[q]);
            }
        }
    }
}

// ---------------- K5: inverse rfft over w via bf16 MFMA + bias ---------------
// 256 thr / 4 waves; bias folded into MFMA C-in; 8 bh per block.
#define APITCH 72
__global__ __launch_bounds__(256) void k5_idft_w(const float* __restrict__ bias,
                                                 const float* __restrict__ WS,
                                                 float* __restrict__ out) {
    int t = threadIdx.x;
    __shared__ float2 tw[256];
    __shared__ unsigned short T5[256 * APITCH];  // [w][k] bf16, 36 KB
    __shared__ unsigned short Bl[64 * APITCH];   // [o][k] bf16, 9 KB
    { float s, c; sincosf(TWO_PI * (float)t * (1.0f/256.0f), &s, &c);
      tw[t] = make_float2(c, s); }
    __syncthreads();
    {   // build T5 row w = t
        int w = t;
#pragma unroll
        for (int ky = 0; ky < 32; ++ky) {
            float2 cs = tw[(ky * w) & 255];
            float sc = ky ? 2.f : 1.f;
            T5[w*APITCH + ky]      = f2bf(sc * cs.x);
            T5[w*APITCH + 32 + ky] = f2bf(-sc * cs.y);
        }
    }
    int o = t & 63, kg = t >> 6;     // staging roles
    int wave = t >> 6, col = t & 15, kq = (t >> 4) & 3;
    float bv[4];
#pragma unroll
    for (int n = 0; n < 4; ++n) bv[n] = bias[n*16 + col];

    for (int u = 0; u < 8; ++u) {
        int bh = blockIdx.x * 8 + u;
        __syncthreads();             // prior MFMA reads done (u=0: T5 ready)
        {   // stage Bl[o][k] from tmp row (u32 bf16 pairs, pure bit-copy)
            const unsigned int* tpu = (const unsigned int*)WS + (size_t)bh * 2048;
#pragma unroll
            for (int kk = 0; kk < 8; ++kk) {
                int ky = kg*8 + kk;
                unsigned int g = tpu[ky*64 + o];
                Bl[o*APITCH + ky]      = (unsigned short)(g & 0xffffu);
                Bl[o*APITCH + 32 + ky] = (unsigned short)(g >> 16);
            }
        }
        __syncthreads();
        f32x4 acc[4][4];             // [m-tile][n-tile], C-in = bias
#pragma unroll
        for (int mt = 0; mt < 4; ++mt)
#pragma unroll
            for (int n = 0; n < 4; ++n)
                acc[mt][n] = (f32x4){bv[n], bv[n], bv[n], bv[n]};
#pragma unroll
        for (int kk = 0; kk < 2; ++kk) {
            short8 af[4];
#pragma unroll
            for (int mt = 0; mt < 4; ++mt)
                af[mt] = *(const short8*)&T5[(wave*64 + mt*16 + col)*APITCH
                                             + kk*32 + kq*8];
#pragma unroll
            for (int n = 0; n < 4; ++n) {
                short8 bf = *(const short8*)&Bl[(n*16 + col)*APITCH
                                                + kk*32 + kq*8];
#pragma unroll
                for (int mt = 0; mt < 4; ++mt)
                    acc[mt][n] = __builtin_amdgcn_mfma_f32_16x16x32_bf16(
                                     af[mt], bf, acc[mt][n], 0, 0, 0);
            }
        }
        float* R = out + (size_t)bh * 16384;
#pragma unroll
        for (int mt = 0; mt < 4; ++mt)
#pragma unroll
            for (int n = 0; n < 4; ++n)
#pragma unroll
                for (int q = 0; q < 4; ++q) {
                    int w = wave*64 + mt*16 + kq*4 + q;
                    R[w*64 + n*16 + col] = acc[mt][n][q];
                }
    }
}

extern "C" void kernel_launch(void* const* d_in, const int* in_sizes, int n_in,
                              void* d_out, int out_size, void* d_ws, size_t ws_size,
                              hipStream_t stream) {
    (void)in_sizes; (void)n_in; (void)out_size;
    if (ws_size < WS_FLOATS_NEEDED * sizeof(float)) return;  // ws observed = 1 GiB
    const float* x    = (const float*)d_in[0];
    const float* w1re = (const float*)d_in[1];
    const float* w1im = (const float*)d_in[2];
    const float* w2re = (const float*)d_in[3];
    const float* w2im = (const float*)d_in[4];
    const float* bias = (const float*)d_in[5];
    float* O  = (float*)d_out;
    float* WS = (float*)d_ws;

    k1_dft_w <<< 512,  512, 0, stream>>>(x, WS);
    k2_dft_h <<< 256, 1024, 0, stream>>>(WS);
    k3_mix   <<< 256,  512, 0, stream>>>(w1re, w1im, w2re, w2im, WS);
    k4_idft_h<<< 256, 1024, 0, stream>>>(WS);
    k5_idft_w<<< 512,  256, 0, stream>>>(bias, WS, O);
}